// Round 6
// baseline (2805.587 us; speedup 1.0000x reference)
//
#include <hip/hip_runtime.h>
#include <cstdint>
#include <cstddef>

// ---------------------------------------------------------------------------
// y = x @ W^T + lb  [B=32768, C=2048], K=2048 ; GroupNorm(32 groups of 64) ;
// per-row min ; out[0,c,b,0] = mins[b] + final_bias[c].
//
// R6: 2 blocks/CU. 256x256 tile, BK=32 -> 64 KB LDS (2 buf x 32 KB) ->
// two independent (non-barrier-synced) blocks per CU overlap each other's
// read/drain phases with MFMA phases. XCD swizzle REVERTED (identity map
// keeps each XCD's concurrent blocks on one B-panel -> L2-resident; the
// swizzle's 8-MB B working set thrashed L2 and cost ~15-20us in R4/R5).
// R5's 2-barrier within-tile pipeline kept: reads split around MFMA
// quadrants, lgkm0+barrier (buf free), stage t+2 (4 loads), Q3/Q4
// register-only, vmcnt(4)+barrier boundary (never 0 mid-loop).
// ---------------------------------------------------------------------------

#define AS1C(p) ((const __attribute__((address_space(1))) void*)(p))
#define AS3(p)  ((__attribute__((address_space(3))) void*)(p))
#define SB0()   __builtin_amdgcn_sched_barrier(0)

typedef short  short8  __attribute__((ext_vector_type(8)));
typedef int    int4v   __attribute__((ext_vector_type(4)));
typedef float  f32x4   __attribute__((ext_vector_type(4)));
typedef unsigned short ushort8 __attribute__((ext_vector_type(8)));

static constexpr int BDIM = 32768;
static constexpr int KDIM = 2048;
static constexpr int CDIM = 2048;
static constexpr int NT   = KDIM / 32;    // 64 K-tiles of BK=32

// ----------------------------- helpers -------------------------------------

__device__ __forceinline__ unsigned short f2bf(float f) {
    unsigned u = __float_as_uint(f);
    u += 0x7FFFu + ((u >> 16) & 1u);   // RNE
    return (unsigned short)(u >> 16);
}

__device__ __forceinline__ unsigned enc_min(float f) {
    unsigned u = __float_as_uint(f);
    return (u & 0x80000000u) ? ~u : (u | 0x80000000u);  // monotone float->uint
}

__device__ __forceinline__ float dec_min(unsigned e) {
    unsigned u = (e & 0x80000000u) ? (e ^ 0x80000000u) : ~e;
    return __uint_as_float(u);
}

// ----------------------------- k1: convert ---------------------------------

__global__ void convert_kernel(const float* __restrict__ src,
                               unsigned short* __restrict__ dst, int n8) {
    int i = blockIdx.x * blockDim.x + threadIdx.x;
    if (i >= n8) return;
    const float4* s4 = (const float4*)src;
    float4 a = s4[2 * i];
    float4 b = s4[2 * i + 1];
    ushort8 o;
    o[0] = f2bf(a.x); o[1] = f2bf(a.y); o[2] = f2bf(a.z); o[3] = f2bf(a.w);
    o[4] = f2bf(b.x); o[5] = f2bf(b.y); o[6] = f2bf(b.z); o[7] = f2bf(b.w);
    ((ushort8*)dst)[i] = o;
}

// ------------------- k2: fused GEMM + GroupNorm + row-min -------------------

__global__ __launch_bounds__(512, 4) void gemm_gn_min(
    const unsigned short* __restrict__ Abf,   // x [32768,2048] bf16
    const unsigned short* __restrict__ Wbf,   // W [2048,2048]  bf16
    const float* __restrict__ lb,
    const float* __restrict__ gw,
    const float* __restrict__ gb,
    unsigned int* mins_enc)
{
    // buf d (32 KB): A at d*32768 (256 rows x 64B), B at d*32768+16384
    __shared__ unsigned char lds[65536];

    const int tid  = threadIdx.x;
    const int wid  = tid >> 6;
    const int lane = tid & 63;

    // identity mapping: XCD x's concurrent blocks share bj==x -> B-panel
    // (1 MB) L2-resident. (XCD swizzle measured as a regression here.)
    const int bj  = blockIdx.x & 7;           // C/256 = 8
    const int bi  = blockIdx.x >> 3;          // B/256 = 128
    const int row0 = bi * 256, col0 = bj * 256;
    const int wr = wid >> 2, wc = wid & 3;

    const int lrow = lane & 15;
    const int lq   = lane >> 4;               // K-chunk of this lane's frag

    // staging: half-tile = 128 rows x 32 K x 2B = 8 KB = 1 load/thread.
    // Wave wid covers rows [wid*16, wid*16+16): lane l -> row wid*16 + (l>>2),
    // physical chunk l&3. Inverse-swizzled global source so that LDS
    // physical chunk p of row r holds logical chunk p ^ ((r>>1)&3).
    const int schunk = (lane & 3) ^ ((lane >> 3) & 3);
    const unsigned short* aSrc =
        Abf + (size_t)(row0 + wid * 16 + (lane >> 2)) * KDIM + schunk * 8;
    const unsigned short* bSrc =
        Wbf + (size_t)(col0 + wid * 16 + (lane >> 2)) * KDIM + schunk * 8;

    auto stageAh = [&](int d, int kt, int h) {
        __builtin_amdgcn_global_load_lds(
            AS1C(aSrc + (size_t)(h * 128) * KDIM + kt * 32),
            AS3(&lds[d * 32768 + (h * 128 + wid * 16) * 64]), 16, 0, 0);
    };
    auto stageBh = [&](int d, int kt, int h) {
        __builtin_amdgcn_global_load_lds(
            AS1C(bSrc + (size_t)(h * 128) * KDIM + kt * 32),
            AS3(&lds[d * 32768 + 16384 + (h * 128 + wid * 16) * 64]), 16, 0, 0);
    };

    // read: row r, K-chunk lq -> physical chunk lq ^ ((r>>1)&3)
    auto rdA = [&](int d, int r) -> int4v {
        return *(const int4v*)&lds[d * 32768 + r * 64 + ((lq ^ ((r >> 1) & 3))) * 16];
    };
    auto rdB = [&](int d, int r) -> int4v {
        return *(const int4v*)&lds[d * 32768 + 16384 + r * 64 +
                                   ((lq ^ ((r >> 1) & 3))) * 16];
    };

    f32x4 acc[8][4] = {};
    int4v a03[4], a47[4], b01[2], b23[2];

    // ---- prologue: buf0 <- tile 0, buf1 <- tile 1 (8 loads);
    // wait for the oldest 4 (tile 0); tile 1's 4 stay in flight.
    stageAh(0, 0, 0); stageAh(0, 0, 1); stageBh(0, 0, 0); stageBh(0, 0, 1);
    stageAh(1, 1, 0); stageAh(1, 1, 1); stageBh(1, 1, 0); stageBh(1, 1, 1);
    asm volatile("s_waitcnt vmcnt(4)" ::: "memory");
    __builtin_amdgcn_s_barrier();
    asm volatile("" ::: "memory");

    for (int t = 0; t < NT; ++t) {
        const int c = t & 1;
        const bool st2 = (t + 2 < NT);

        // -------- R1: a03 (4) + b01 (2) reads
#pragma unroll
        for (int m = 0; m < 4; ++m)
            a03[m] = rdA(c, wr * 128 + m * 16 + lrow);
#pragma unroll
        for (int n = 0; n < 2; ++n)
            b01[n] = rdB(c, wc * 64 + n * 16 + lrow);
        SB0();
        // -------- R2: a47 (4) reads (fly under Q1)
#pragma unroll
        for (int m = 0; m < 4; ++m)
            a47[m] = rdA(c, wr * 128 + (m + 4) * 16 + lrow);
        SB0();
        // -------- Q1: m0-3 x n0-1 (compiler-counted lgkm gates a03/b01)
        __builtin_amdgcn_s_setprio(1);
#pragma unroll
        for (int m = 0; m < 4; ++m)
#pragma unroll
            for (int n = 0; n < 2; ++n)
                acc[m][n] = __builtin_amdgcn_mfma_f32_16x16x32_bf16(
                    __builtin_bit_cast(short8, a03[m]),
                    __builtin_bit_cast(short8, b01[n]),
                    acc[m][n], 0, 0, 0);
        __builtin_amdgcn_s_setprio(0);
        SB0();
        // -------- R3: b23 (2) reads (fly under Q2)
#pragma unroll
        for (int n = 0; n < 2; ++n)
            b23[n] = rdB(c, wc * 64 + (n + 2) * 16 + lrow);
        SB0();
        // -------- Q2: m4-7 x n0-1
        __builtin_amdgcn_s_setprio(1);
#pragma unroll
        for (int m = 0; m < 4; ++m)
#pragma unroll
            for (int n = 0; n < 2; ++n)
                acc[m + 4][n] = __builtin_amdgcn_mfma_f32_16x16x32_bf16(
                    __builtin_bit_cast(short8, a47[m]),
                    __builtin_bit_cast(short8, b01[n]),
                    acc[m + 4][n], 0, 0, 0);
        __builtin_amdgcn_s_setprio(0);
        SB0();
        // -------- barrier A: all waves fully read buf c -> buf c free
        asm volatile("s_waitcnt lgkmcnt(0)" ::: "memory");
        __builtin_amdgcn_s_barrier();
        asm volatile("" ::: "memory");
        // -------- stage whole tile t+2 into buf c (4 loads)
        if (st2) {
            stageAh(c, t + 2, 0); stageAh(c, t + 2, 1);
            stageBh(c, t + 2, 0); stageBh(c, t + 2, 1);
        }
        SB0();
        // -------- Q3 + Q4: n2-3 (register-only; stages fly under)
        __builtin_amdgcn_s_setprio(1);
#pragma unroll
        for (int m = 0; m < 4; ++m)
#pragma unroll
            for (int n = 0; n < 2; ++n)
                acc[m][n + 2] = __builtin_amdgcn_mfma_f32_16x16x32_bf16(
                    __builtin_bit_cast(short8, a03[m]),
                    __builtin_bit_cast(short8, b23[n]),
                    acc[m][n + 2], 0, 0, 0);
#pragma unroll
        for (int m = 0; m < 4; ++m)
#pragma unroll
            for (int n = 0; n < 2; ++n)
                acc[m + 4][n + 2] = __builtin_amdgcn_mfma_f32_16x16x32_bf16(
                    __builtin_bit_cast(short8, a47[m]),
                    __builtin_bit_cast(short8, b23[n]),
                    acc[m + 4][n + 2], 0, 0, 0);
        __builtin_amdgcn_s_setprio(0);
        SB0();
        // -------- boundary: t+1's 4 loads are the oldest -> complete
        if (st2) asm volatile("s_waitcnt vmcnt(4)" ::: "memory");
        else     asm volatile("s_waitcnt vmcnt(0)" ::: "memory");
        __builtin_amdgcn_s_barrier();
        asm volatile("" ::: "memory");
    }

    // ---- epilogue: +bias, groupnorm over this wave's 64-col group, row min
    float lbv[4], gwv[4], gbv[4];
    const int cbase = col0 + wc * 64 + lrow;
#pragma unroll
    for (int n = 0; n < 4; ++n) {
        int c = cbase + n * 16;
        lbv[n] = lb[c]; gwv[n] = gw[c]; gbv[n] = gb[c];
    }

#pragma unroll
    for (int m = 0; m < 8; ++m) {
#pragma unroll
        for (int i = 0; i < 4; ++i) {
            float v[4];
            float s1 = 0.f, s2 = 0.f;
#pragma unroll
            for (int n = 0; n < 4; ++n) {
                v[n] = acc[m][n][i] + lbv[n];
                s1 += v[n];
                s2 += v[n] * v[n];
            }
#pragma unroll
            for (int mask = 1; mask <= 8; mask <<= 1) {
                s1 += __shfl_xor(s1, mask, 64);
                s2 += __shfl_xor(s2, mask, 64);
            }
            float mean = s1 * (1.f / 64.f);
            float var  = s2 * (1.f / 64.f) - mean * mean;
            float rstd = rsqrtf(var + 1e-5f);
            float mn = 3.4e38f;
#pragma unroll
            for (int n = 0; n < 4; ++n) {
                float nv = (v[n] - mean) * rstd * gwv[n] + gbv[n];
                mn = fminf(mn, nv);
            }
#pragma unroll
            for (int mask = 1; mask <= 8; mask <<= 1)
                mn = fminf(mn, __shfl_xor(mn, mask, 64));
            if (lrow == 0) {
                int row = row0 + wr * 128 + m * 16 + lq * 4 + i;
                atomicMin(mins_enc + row, enc_min(mn));
            }
        }
    }
}

// --------------------------- k3: broadcast ----------------------------------

__global__ void finalize_kernel(const unsigned int* mins_enc,
                                const float* __restrict__ fb, float* out) {
    size_t t = (size_t)blockIdx.x * 256 + threadIdx.x;
    size_t flat = t * 4;                      // 4 consecutive b, same c
    int c = (int)(flat >> 15);
    if (c == 1088) return;                    // mins live here; fixup later
    int b = (int)(flat & 32767);
    uint4 e = *(const uint4*)(mins_enc + b);
    float bias = fb[c];
    float4 o;
    o.x = dec_min(e.x) + bias;
    o.y = dec_min(e.y) + bias;
    o.z = dec_min(e.z) + bias;
    o.w = dec_min(e.w) + bias;
    *(float4*)(out + flat) = o;
}

__global__ void fixup_kernel(const float* __restrict__ fb, float* out) {
    int b = blockIdx.x * 256 + threadIdx.x;
    size_t idx = (size_t)1088 * 32768 + b;
    unsigned e = ((const unsigned*)out)[idx];  // read own cell first
    out[idx] = dec_min(e) + fb[1088];
}

// ----------------------------- launcher -------------------------------------

extern "C" void kernel_launch(void* const* d_in, const int* in_sizes, int n_in,
                              void* d_out, int out_size, void* d_ws, size_t ws_size,
                              hipStream_t stream) {
    const float* x  = (const float*)d_in[0];
    const float* w  = (const float*)d_in[1];
    const float* lb = (const float*)d_in[2];
    const float* gw = (const float*)d_in[3];
    const float* gb = (const float*)d_in[4];
    const float* fb = (const float*)d_in[5];
    float* out = (float*)d_out;

    // scratch regions inside d_out (268 MB total):
    unsigned short* xb = (unsigned short*)d_out;                        // 128 MiB
    unsigned short* wb = (unsigned short*)((char*)d_out + 134217728);   //   8 MiB
    unsigned int* mins = (unsigned int*)((char*)d_out + (size_t)1088 * 32768 * 4);

    // k1: fp32 -> bf16
    {
        int n8 = (BDIM * KDIM) / 8;
        convert_kernel<<<(n8 + 255) / 256, 256, 0, stream>>>(x, xb, n8);
    }
    {
        int n8 = (CDIM * KDIM) / 8;
        convert_kernel<<<(n8 + 255) / 256, 256, 0, stream>>>(w, wb, n8);
    }

    // init encoded mins to 0xFFFFFFFF (>= every encoding)
    hipMemsetAsync((void*)mins, 0xFF, (size_t)BDIM * 4, stream);

    // k2: fused GEMM + GN + min  (256x256 tiles -> 128x8 = 1024 blocks)
    gemm_gn_min<<<dim3((BDIM / 256) * (CDIM / 256)), dim3(512), 0, stream>>>(
        xb, wb, lb, gw, gb, mins);

    // k3: broadcast (skips c==1088), then fixup c==1088
    finalize_kernel<<<(BDIM / 4) * CDIM / 256, 256, 0, stream>>>(mins, fb, out);
    fixup_kernel<<<BDIM / 256, 256, 0, stream>>>(fb, out);
}

// Round 7
// 429.285 us; speedup vs baseline: 6.5355x; 6.5355x over previous
//
#include <hip/hip_runtime.h>
#include <cstdint>
#include <cstddef>

// ---------------------------------------------------------------------------
// y = x @ W^T + lb  [B=32768, C=2048], K=2048 ; GroupNorm(32 groups of 64) ;
// per-row min ; out[0,c,b,0] = mins[b] + final_bias[c].
//
// R7: 2 blocks/CU with a register-sized tile. R6's failure was acc spilling
// (WRITE_SIZE 7.4 GB): 256x256 tile needs ~180 VGPR vs the 128 cap at
// 4 waves/EU. Fix: BM=128 x BN=256, 8 waves 2Mx4N -> wave owns 64x64,
// acc[4][4]=64 VGPR, total ~115 < 128. BK=32, LDS 48 KB -> 2 blocks/CU.
// Two independent blocks per CU overlap each other's LDS-read/drain/barrier
// windows with MFMA windows (m114: separate waves co-schedule MFMA+VALU).
// Per tile: {rd a03+b01 | Q1 | rd b23 | lgkm0+bar | stage t+2 (3 loads) |
// Q2 reg-only | vmcnt(3)+bar}. Identity bj mapping (B-panel L2-resident).
// ---------------------------------------------------------------------------

#define AS1C(p) ((const __attribute__((address_space(1))) void*)(p))
#define AS3(p)  ((__attribute__((address_space(3))) void*)(p))
#define SB0()   __builtin_amdgcn_sched_barrier(0)

typedef short  short8  __attribute__((ext_vector_type(8)));
typedef int    int4v   __attribute__((ext_vector_type(4)));
typedef float  f32x4   __attribute__((ext_vector_type(4)));
typedef unsigned short ushort8 __attribute__((ext_vector_type(8)));

static constexpr int BDIM = 32768;
static constexpr int KDIM = 2048;
static constexpr int CDIM = 2048;
static constexpr int NT   = KDIM / 32;    // 64 K-tiles of BK=32

// ----------------------------- helpers -------------------------------------

__device__ __forceinline__ unsigned short f2bf(float f) {
    unsigned u = __float_as_uint(f);
    u += 0x7FFFu + ((u >> 16) & 1u);   // RNE
    return (unsigned short)(u >> 16);
}

__device__ __forceinline__ unsigned enc_min(float f) {
    unsigned u = __float_as_uint(f);
    return (u & 0x80000000u) ? ~u : (u | 0x80000000u);  // monotone float->uint
}

__device__ __forceinline__ float dec_min(unsigned e) {
    unsigned u = (e & 0x80000000u) ? (e ^ 0x80000000u) : ~e;
    return __uint_as_float(u);
}

// ----------------------------- k1: convert ---------------------------------

__global__ void convert_kernel(const float* __restrict__ src,
                               unsigned short* __restrict__ dst, int n8) {
    int i = blockIdx.x * blockDim.x + threadIdx.x;
    if (i >= n8) return;
    const float4* s4 = (const float4*)src;
    float4 a = s4[2 * i];
    float4 b = s4[2 * i + 1];
    ushort8 o;
    o[0] = f2bf(a.x); o[1] = f2bf(a.y); o[2] = f2bf(a.z); o[3] = f2bf(a.w);
    o[4] = f2bf(b.x); o[5] = f2bf(b.y); o[6] = f2bf(b.z); o[7] = f2bf(b.w);
    ((ushort8*)dst)[i] = o;
}

// ------------------- k2: fused GEMM + GroupNorm + row-min -------------------

__global__ __launch_bounds__(512, 4) void gemm_gn_min(
    const unsigned short* __restrict__ Abf,   // x [32768,2048] bf16
    const unsigned short* __restrict__ Wbf,   // W [2048,2048]  bf16
    const float* __restrict__ lb,
    const float* __restrict__ gw,
    const float* __restrict__ gb,
    unsigned int* mins_enc)
{
    // buf d (24 KB): A at d*24576 (128 rows x 64B), B at d*24576+8192 (256x64B)
    __shared__ unsigned char lds[49152];

    const int tid  = threadIdx.x;
    const int wid  = tid >> 6;
    const int lane = tid & 63;

    // identity mapping: XCD x's concurrent blocks share bj==x -> B-panel
    // L2-resident (XCD swizzle measured as a regression in R4/R5).
    const int bj  = blockIdx.x & 7;           // C/256 = 8
    const int bi  = blockIdx.x >> 3;          // B/128 = 256
    const int row0 = bi * 128, col0 = bj * 256;
    const int wr = wid >> 2, wc = wid & 3;    // 2M x 4N, wave owns 64x64

    const int lrow = lane & 15;
    const int lq   = lane >> 4;               // K-chunk (16B) of this lane

    // staging: A tile = 128 rows x 64 B = 8 KB = 1 load/thread (512 x 16 B).
    // Wave wid covers rows [wid*16, wid*16+16): lane l -> row wid*16+(l>>2),
    // physical chunk l&3. Inverse-swizzled global source so LDS physical
    // chunk p of row r holds logical chunk p ^ ((r>>1)&3).
    const int schunk = (lane & 3) ^ ((lane >> 3) & 3);
    const unsigned short* aSrc =
        Abf + (size_t)(row0 + wid * 16 + (lane >> 2)) * KDIM + schunk * 8;
    const unsigned short* bSrc =
        Wbf + (size_t)(col0 + wid * 16 + (lane >> 2)) * KDIM + schunk * 8;

    auto stageA = [&](int d, int kt) {
        __builtin_amdgcn_global_load_lds(
            AS1C(aSrc + kt * 32),
            AS3(&lds[d * 24576 + (wid * 16) * 64]), 16, 0, 0);
    };
    auto stageBh = [&](int d, int kt, int h) {
        __builtin_amdgcn_global_load_lds(
            AS1C(bSrc + (size_t)(h * 128) * KDIM + kt * 32),
            AS3(&lds[d * 24576 + 8192 + (h * 128 + wid * 16) * 64]), 16, 0, 0);
    };

    // read: row r, K-chunk lq -> physical chunk lq ^ ((r>>1)&3)
    auto rdA = [&](int d, int r) -> int4v {
        return *(const int4v*)&lds[d * 24576 + r * 64 +
                                   ((lq ^ ((r >> 1) & 3))) * 16];
    };
    auto rdB = [&](int d, int r) -> int4v {
        return *(const int4v*)&lds[d * 24576 + 8192 + r * 64 +
                                   ((lq ^ ((r >> 1) & 3))) * 16];
    };

    f32x4 acc[4][4] = {};
    int4v a[4], b[4];

    // ---- prologue: buf0 <- tile 0, buf1 <- tile 1 (6 loads);
    // wait for the oldest 3 (tile 0); tile 1's 3 stay in flight.
    stageA(0, 0); stageBh(0, 0, 0); stageBh(0, 0, 1);
    stageA(1, 1); stageBh(1, 1, 0); stageBh(1, 1, 1);
    asm volatile("s_waitcnt vmcnt(3)" ::: "memory");
    __builtin_amdgcn_s_barrier();
    asm volatile("" ::: "memory");

    for (int t = 0; t < NT; ++t) {
        const int c = t & 1;
        const bool st2 = (t + 2 < NT);

        // -------- R1: a0-3 (4) + b01 (2) reads
#pragma unroll
        for (int m = 0; m < 4; ++m)
            a[m] = rdA(c, wr * 64 + m * 16 + lrow);
#pragma unroll
        for (int n = 0; n < 2; ++n)
            b[n] = rdB(c, wc * 64 + n * 16 + lrow);
        SB0();
        // -------- Q1: m0-3 x n0-1 (compiler-counted lgkm gates a/b01)
        __builtin_amdgcn_s_setprio(1);
#pragma unroll
        for (int m = 0; m < 4; ++m)
#pragma unroll
            for (int n = 0; n < 2; ++n)
                acc[m][n] = __builtin_amdgcn_mfma_f32_16x16x32_bf16(
                    __builtin_bit_cast(short8, a[m]),
                    __builtin_bit_cast(short8, b[n]),
                    acc[m][n], 0, 0, 0);
        __builtin_amdgcn_s_setprio(0);
        SB0();
        // -------- R2: b23 (2) reads
#pragma unroll
        for (int n = 2; n < 4; ++n)
            b[n] = rdB(c, wc * 64 + n * 16 + lrow);
        SB0();
        // -------- barrier A: all waves fully read buf c -> buf c free
        asm volatile("s_waitcnt lgkmcnt(0)" ::: "memory");
        __builtin_amdgcn_s_barrier();
        asm volatile("" ::: "memory");
        // -------- stage whole tile t+2 into buf c (3 loads)
        if (st2) {
            stageA(c, t + 2); stageBh(c, t + 2, 0); stageBh(c, t + 2, 1);
        }
        SB0();
        // -------- Q2: m0-3 x n2-3 (register-only; stages fly under)
        __builtin_amdgcn_s_setprio(1);
#pragma unroll
        for (int m = 0; m < 4; ++m)
#pragma unroll
            for (int n = 2; n < 4; ++n)
                acc[m][n] = __builtin_amdgcn_mfma_f32_16x16x32_bf16(
                    __builtin_bit_cast(short8, a[m]),
                    __builtin_bit_cast(short8, b[n]),
                    acc[m][n], 0, 0, 0);
        __builtin_amdgcn_s_setprio(0);
        SB0();
        // -------- boundary: t+1's 3 loads are the oldest -> complete
        if (st2) asm volatile("s_waitcnt vmcnt(3)" ::: "memory");
        else     asm volatile("s_waitcnt vmcnt(0)" ::: "memory");
        __builtin_amdgcn_s_barrier();
        asm volatile("" ::: "memory");
    }

    // ---- epilogue: +bias, groupnorm over this wave's 64-col group, row min
    float lbv[4], gwv[4], gbv[4];
    const int cbase = col0 + wc * 64 + lrow;
#pragma unroll
    for (int n = 0; n < 4; ++n) {
        int ch = cbase + n * 16;
        lbv[n] = lb[ch]; gwv[n] = gw[ch]; gbv[n] = gb[ch];
    }

#pragma unroll
    for (int m = 0; m < 4; ++m) {
#pragma unroll
        for (int i = 0; i < 4; ++i) {
            float v[4];
            float s1 = 0.f, s2 = 0.f;
#pragma unroll
            for (int n = 0; n < 4; ++n) {
                v[n] = acc[m][n][i] + lbv[n];
                s1 += v[n];
                s2 += v[n] * v[n];
            }
#pragma unroll
            for (int mask = 1; mask <= 8; mask <<= 1) {
                s1 += __shfl_xor(s1, mask, 64);
                s2 += __shfl_xor(s2, mask, 64);
            }
            float mean = s1 * (1.f / 64.f);
            float var  = s2 * (1.f / 64.f) - mean * mean;
            float rstd = rsqrtf(var + 1e-5f);
            float mn = 3.4e38f;
#pragma unroll
            for (int n = 0; n < 4; ++n) {
                float nv = (v[n] - mean) * rstd * gwv[n] + gbv[n];
                mn = fminf(mn, nv);
            }
#pragma unroll
            for (int mask = 1; mask <= 8; mask <<= 1)
                mn = fminf(mn, __shfl_xor(mn, mask, 64));
            if (lrow == 0) {
                int row = row0 + wr * 64 + m * 16 + lq * 4 + i;
                atomicMin(mins_enc + row, enc_min(mn));
            }
        }
    }
}

// --------------------------- k3: broadcast ----------------------------------

__global__ void finalize_kernel(const unsigned int* mins_enc,
                                const float* __restrict__ fb, float* out) {
    size_t t = (size_t)blockIdx.x * 256 + threadIdx.x;
    size_t flat = t * 4;                      // 4 consecutive b, same c
    int c = (int)(flat >> 15);
    if (c == 1088) return;                    // mins live here; fixup later
    int b = (int)(flat & 32767);
    uint4 e = *(const uint4*)(mins_enc + b);
    float bias = fb[c];
    float4 o;
    o.x = dec_min(e.x) + bias;
    o.y = dec_min(e.y) + bias;
    o.z = dec_min(e.z) + bias;
    o.w = dec_min(e.w) + bias;
    *(float4*)(out + flat) = o;
}

__global__ void fixup_kernel(const float* __restrict__ fb, float* out) {
    int b = blockIdx.x * 256 + threadIdx.x;
    size_t idx = (size_t)1088 * 32768 + b;
    unsigned e = ((const unsigned*)out)[idx];  // read own cell first
    out[idx] = dec_min(e) + fb[1088];
}

// ----------------------------- launcher -------------------------------------

extern "C" void kernel_launch(void* const* d_in, const int* in_sizes, int n_in,
                              void* d_out, int out_size, void* d_ws, size_t ws_size,
                              hipStream_t stream) {
    const float* x  = (const float*)d_in[0];
    const float* w  = (const float*)d_in[1];
    const float* lb = (const float*)d_in[2];
    const float* gw = (const float*)d_in[3];
    const float* gb = (const float*)d_in[4];
    const float* fb = (const float*)d_in[5];
    float* out = (float*)d_out;

    // scratch regions inside d_out (268 MB total):
    unsigned short* xb = (unsigned short*)d_out;                        // 128 MiB
    unsigned short* wb = (unsigned short*)((char*)d_out + 134217728);   //   8 MiB
    unsigned int* mins = (unsigned int*)((char*)d_out + (size_t)1088 * 32768 * 4);

    // k1: fp32 -> bf16
    {
        int n8 = (BDIM * KDIM) / 8;
        convert_kernel<<<(n8 + 255) / 256, 256, 0, stream>>>(x, xb, n8);
    }
    {
        int n8 = (CDIM * KDIM) / 8;
        convert_kernel<<<(n8 + 255) / 256, 256, 0, stream>>>(w, wb, n8);
    }

    // init encoded mins to 0xFFFFFFFF (>= every encoding)
    hipMemsetAsync((void*)mins, 0xFF, (size_t)BDIM * 4, stream);

    // k2: fused GEMM + GN + min  (128x256 tiles -> 256x8 = 2048 blocks)
    gemm_gn_min<<<dim3((BDIM / 128) * (CDIM / 256)), dim3(512), 0, stream>>>(
        xb, wb, lb, gw, gb, mins);

    // k3: broadcast (skips c==1088), then fixup c==1088
    finalize_kernel<<<(BDIM / 4) * CDIM / 256, 256, 0, stream>>>(mins, fb, out);
    fixup_kernel<<<BDIM / 256, 256, 0, stream>>>(fb, out);
}